// Round 13
// baseline (143.549 us; speedup 1.0000x reference)
//
#include <hip/hip_runtime.h>
#include <cstddef>

#define NSRC 50000
#define NDST 50000
#define NEDGE 500000
#define DIM 128
#define EDIM 11
#define BN_EPS 1e-5f
#define SCAN_NBLK ((NDST + 255) / 256)   // 196

#define HS_BLOCKS ((NSRC + 63) / 64)      // 782 (GEMM, 64 rows/block)
#define SCORE_BLK ((NDST + 63) / 64)      // 782 (score matvec, 64 rows/block)
#define EDB       ((NEDGE + 511) / 512)   // 977 (edge pass, 2 edges/thread)
#define SC_BLOCKS ((NEDGE + 1023) / 1024) // 489 (k_scat, 4 edges/thread)
#define FUSE_GRID (196 * 9)               // 4 GEMM + 5 edge per group; 784>=782, 980>=977

typedef short bf16x8 __attribute__((ext_vector_type(8)));
typedef float f32x4 __attribute__((ext_vector_type(4)));

// ---------------- workspace layout (4B elems) ----------------
#define OFF_HS       0                                   // bf16[NSRC][DIM]
#define OFF_SSCORE   (OFF_HS + (size_t)NSRC*DIM/2)
#define OFF_DSCORE   (OFF_SSCORE + NSRC)
#define OFF_DEG16    (OFF_DSCORE + NDST)                 // int[NDST*16] padded counters
#define OFF_COLSUM   (OFF_DEG16 + (size_t)NDST*16)       // deg16..colsq contiguous memset
#define OFF_COLSQ    (OFF_COLSUM + 128)
#define OFF_OFFS     (OFF_COLSQ + 128)                   // offL[NDST] (local prefixes)
#define OFF_REW      (OFF_OFFS + NDST + 2)               // int2[NEDGE]: (rank, ew bits)
#define OFF_PAIRS    (OFF_REW + 2*(size_t)NEDGE)         // int2[NEDGE]
#define OFF_WDVEC    (OFF_PAIRS + 2*(size_t)NEDGE)
#define OFF_WEVEC    (OFF_WDVEC + 128)
#define OFF_SCAL     (OFF_WEVEC + 16)
#define OFF_WSVEC    (OFF_SCAL + 4)
#define OFF_PART     (OFF_WSVEC + 128)
#define OFF_WT       (((OFF_PART + 256 + 3) / 4) * 4)    // 16B-aligned; bf16[128][128]

// fp32 -> bf16 round-to-nearest-even
__device__ __forceinline__ unsigned short f2bf(float x) {
    unsigned int u = __float_as_uint(x);
    u += 0x7FFFu + ((u >> 16) & 1u);
    return (unsigned short)(u >> 16);
}
__device__ __forceinline__ float bf2f(unsigned int u16) {
    return __uint_as_float(u16 << 16);
}

// merged prep + Wt transpose:
// bb=0: wd_vec=W_dst@aw_d, scal[0];  bb=1: we_vec=W_edge@aw_e, scal[1];
// bb=2: ws_vec=W_src@aw_s, scal[2];  bb>=3: Wt[c][k]=bf16(W_src[k][c]) tile bb-3.
__global__ __launch_bounds__(256) void k_prepwt(const float* __restrict__ W_dst,
                                                const float* __restrict__ b_dst,
                                                const float* __restrict__ W_edge,
                                                const float* __restrict__ b_edge,
                                                const float* __restrict__ W_src,
                                                const float* __restrict__ b_src,
                                                const float* __restrict__ attn_w,
                                                const float* __restrict__ attn_b,
                                                float* __restrict__ wd_vec,
                                                float* __restrict__ we_vec,
                                                float* __restrict__ ws_vec,
                                                float* __restrict__ scal,
                                                unsigned short* __restrict__ wt) {
    int bb = blockIdx.x;
    int t = threadIdx.x;
    __shared__ float red[128];
    __shared__ float tile[32][33];
    if (bb == 0) {
        if (t < 128) {
            float acc = 0.f;
            for (int d = 0; d < DIM; ++d) acc += W_dst[t * DIM + d] * attn_w[DIM + d];
            wd_vec[t] = acc;
            red[t] = b_dst[t] * attn_w[DIM + t];
        }
        __syncthreads();
        for (int s = 64; s > 0; s >>= 1) { if (t < s) red[t] += red[t + s]; __syncthreads(); }
        if (t == 0) scal[0] = red[0];
    } else if (bb == 1) {
        if (t < 128) {
            if (t < EDIM) {
                float e = 0.f;
                for (int d = 0; d < DIM; ++d) e += W_edge[t * DIM + d] * attn_w[2 * DIM + d];
                we_vec[t] = e;
            }
            red[t] = b_edge[t] * attn_w[2 * DIM + t];
        }
        __syncthreads();
        for (int s = 64; s > 0; s >>= 1) { if (t < s) red[t] += red[t + s]; __syncthreads(); }
        if (t == 0) scal[1] = red[0] + attn_b[0];
    } else if (bb == 2) {
        if (t < 128) {
            float acc = 0.f;
            for (int d = 0; d < DIM; ++d) acc += W_src[t * DIM + d] * attn_w[d];
            ws_vec[t] = acc;
            red[t] = b_src[t] * attn_w[t];
        }
        __syncthreads();
        for (int s = 64; s > 0; s >>= 1) { if (t < s) red[t] += red[t + s]; __syncthreads(); }
        if (t == 0) scal[2] = red[0];
    } else {
        int idx = bb - 3;
        int bi = idx & 3;   // k-tile
        int bj = idx >> 2;  // c-tile
        int cl = t & 31;
        #pragma unroll
        for (int i = 0; i < 4; ++i) {
            int kl = (t >> 5) * 4 + i;
            tile[kl][cl] = W_src[(size_t)(bi * 32 + kl) * DIM + bj * 32 + cl];
        }
        __syncthreads();
        int ko = t & 31;
        #pragma unroll
        for (int i = 0; i < 4; ++i) {
            int co = (t >> 5) * 4 + i;
            wt[(size_t)(bj * 32 + co) * DIM + bi * 32 + ko] = f2bf(tile[ko][co]);
        }
    }
}

// s_score = src_feat.ws_vec + scal[2] ; d_score = dst_feat.wd_vec + scal[0]
// 64 rows/block, 4 lanes/row (32 floats each).
__global__ __launch_bounds__(256) void k_score(const float* __restrict__ src_feat,
                                               const float* __restrict__ dst_feat,
                                               const float* __restrict__ ws_vec,
                                               const float* __restrict__ wd_vec,
                                               const float* __restrict__ scal,
                                               float* __restrict__ s_score,
                                               float* __restrict__ d_score) {
    int bid = blockIdx.x;
    const float* X;
    const float* V;
    float* out;
    float c;
    int r0;
    if (bid < SCORE_BLK) {
        X = src_feat; V = ws_vec; out = s_score; c = scal[2]; r0 = bid * 64;
    } else {
        X = dst_feat; V = wd_vec; out = d_score; c = scal[0]; r0 = (bid - SCORE_BLK) * 64;
    }
    int t = threadIdx.x;
    int row = r0 + (t >> 2);
    int c0 = (t & 3) * 32;
    if (row >= NDST) return;
    const float4* x = reinterpret_cast<const float4*>(X + (size_t)row * DIM + c0);
    const float4* w = reinterpret_cast<const float4*>(V + c0);
    float p = 0.f;
    #pragma unroll
    for (int i = 0; i < 8; ++i) {
        float4 a = x[i], b = w[i];
        p += a.x * b.x + a.y * b.y + a.z * b.z + a.w * b.w;
    }
    p += __shfl_xor(p, 1);
    p += __shfl_xor(p, 2);
    if ((t & 3) == 0) out[row] = p + c;
}

// Fused, 9-block groups (4 GEMM + 5 edge):
//   GEMM: hs = bf16MFMA(src_feat, Wt) + bias -> packed bf16 stores
//   edge (2 edges/thread): full logit + exp; rew[e] = (rank via returning
//   atomic, ew bits) packed in one 8B store.
__global__ __launch_bounds__(256, 2) void k_fused(const float* __restrict__ A,
                                               const unsigned short* __restrict__ wt,
                                               const float* __restrict__ bias,
                                               const float* __restrict__ ef,
                                               const int* __restrict__ src_idx,
                                               const int* __restrict__ dst_idx,
                                               const float* __restrict__ s_score,
                                               const float* __restrict__ d_score,
                                               const float* __restrict__ we_vec,
                                               const float* __restrict__ scal,
                                               unsigned short* __restrict__ hsb,
                                               int2* __restrict__ rew,
                                               int* __restrict__ deg16) {
    const int g = blockIdx.x / 9;
    const int sl = blockIdx.x % 9;
    const int t = threadIdx.x;

    if (sl < 4) {
        // ---- GEMM role: 64x128 output tile, 4 waves x (16 rows x 128 cols) ----
        const int hb = g * 4 + sl;
        if (hb >= HS_BLOCKS) return;
        const int wv = t >> 6;
        const int lane = t & 63;
        const int lrow = lane & 15;
        const int kg = lane >> 4;
        const int grow = hb * 64 + wv * 16 + lrow;
        const bool rowok = grow < NSRC;
        const float* arow = A + (size_t)grow * DIM;

        bf16x8 af[4];
        #pragma unroll
        for (int s = 0; s < 4; ++s) {
            float4 p0 = make_float4(0.f, 0.f, 0.f, 0.f), p1 = p0;
            if (rowok) {
                p0 = *reinterpret_cast<const float4*>(arow + 32 * s + kg * 8);
                p1 = *reinterpret_cast<const float4*>(arow + 32 * s + kg * 8 + 4);
            }
            bf16x8 a;
            a[0] = (short)f2bf(p0.x); a[1] = (short)f2bf(p0.y);
            a[2] = (short)f2bf(p0.z); a[3] = (short)f2bf(p0.w);
            a[4] = (short)f2bf(p1.x); a[5] = (short)f2bf(p1.y);
            a[6] = (short)f2bf(p1.z); a[7] = (short)f2bf(p1.w);
            af[s] = a;
        }

        f32x4 acc[8];
        #pragma unroll
        for (int c = 0; c < 8; ++c) acc[c] = (f32x4){0.f, 0.f, 0.f, 0.f};

        #pragma unroll
        for (int c = 0; c < 8; ++c) {
            #pragma unroll
            for (int s = 0; s < 4; ++s) {
                const bf16x8 b = *reinterpret_cast<const bf16x8*>(
                    wt + ((size_t)(16 * c + lrow) * DIM + 32 * s + kg * 8));
                acc[c] = __builtin_amdgcn_mfma_f32_16x16x32_bf16(af[s], b, acc[c], 0, 0, 0);
            }
        }

        const int orow0 = hb * 64 + wv * 16 + kg * 4;
        #pragma unroll
        for (int c = 0; c < 8; ++c) {
            float bb = bias[16 * c + lrow];
            #pragma unroll
            for (int i = 0; i < 4; ++i) {
                unsigned int mybf = f2bf(acc[c][i] + bb);
                unsigned int nb = (unsigned int)__shfl_xor((int)mybf, 1);
                int orow = orow0 + i;
                if ((lrow & 1) == 0 && orow < NSRC) {
                    *reinterpret_cast<unsigned int*>(hsb + (size_t)orow * DIM + 16 * c + lrow)
                        = (mybf & 0xFFFFu) | (nb << 16);
                }
            }
        }
    } else {
        // ---- edge role: full logit + exp + returning histogram atomic ----
        const int eb = g * 5 + (sl - 4);
        if (eb >= EDB) return;
        float wvv[EDIM];
        #pragma unroll
        for (int k = 0; k < EDIM; ++k) wvv[k] = we_vec[k];
        const float s1 = scal[1];
        int ebase = eb * 512 + t;
        #pragma unroll
        for (int i = 0; i < 2; ++i) {
            int e = ebase + i * 256;
            if (e < NEDGE) {
                int s = src_idx[e], d = dst_idx[e];
                const float* er = ef + (size_t)e * EDIM;
                float a = s1;
                #pragma unroll
                for (int k = 0; k < EDIM; ++k) a += er[k] * wvv[k];
                a += s_score[s] + d_score[d];
                // 0.05-scaled weights => |logit| O(3); exp w/o max-subtraction is
                // exact softmax algebraically and overflow-free here.
                float w = expf(a);
                int r = atomicAdd(&deg16[(size_t)d * 16], 1);
                rew[e] = make_int2(r, __float_as_int(w));
            }
        }
    }
}

// ---- scan: A (per-chunk local prefix + block totals), B (scan totals).
// Final off[i] = offL[i] + part[i>>8], computed on the fly by consumers.
__global__ __launch_bounds__(256) void k_scanA(const int* __restrict__ deg16,
                                               int* __restrict__ offL,
                                               int* __restrict__ partials) {
    __shared__ int tmp[256];
    int t = threadIdx.x;
    int i = blockIdx.x * 256 + t;
    int v = (i < NDST) ? deg16[(size_t)i * 16] : 0;
    tmp[t] = v;
    __syncthreads();
    #pragma unroll
    for (int d = 1; d < 256; d <<= 1) {
        int u = (t >= d) ? tmp[t - d] : 0;
        __syncthreads();
        tmp[t] += u;
        __syncthreads();
    }
    if (i < NDST) offL[i] = tmp[t] - v;
    if (t == 255) partials[blockIdx.x] = tmp[255];
}

__global__ __launch_bounds__(256) void k_scanB(int* __restrict__ partials) {
    __shared__ int tmp[256];
    int t = threadIdx.x;
    int v = (t < SCAN_NBLK) ? partials[t] : 0;
    tmp[t] = v;
    __syncthreads();
    #pragma unroll
    for (int d = 1; d < 256; d <<= 1) {
        int u = (t >= d) ? tmp[t - d] : 0;
        __syncthreads();
        tmp[t] += u;
        __syncthreads();
    }
    if (t < SCAN_NBLK) partials[t] = tmp[t] - v;
}

// pure streaming permutation: pos = offL[d] + part[d>>8] + rank; pairs[pos]=(src,w)
__global__ __launch_bounds__(256) void k_scat(const int* __restrict__ src_idx,
                                              const int* __restrict__ dst_idx,
                                              const int2* __restrict__ rew,
                                              const int* __restrict__ offL,
                                              const int* __restrict__ part,
                                              int2* __restrict__ pairs) {
    int base = blockIdx.x * 1024 + threadIdx.x;
    #pragma unroll
    for (int i = 0; i < 4; ++i) {
        int e = base + i * 256;
        if (e < NEDGE) {
            int d = dst_idx[e];
            int2 r = rew[e];
            int pos = offL[d] + part[d >> 8] + r.x;
            pairs[pos] = make_int2(src_idx[e], r.y);
        }
    }
}

// one wave per dst row, 2 edges per instruction (lanes 0-31 / 32-63).
__global__ __launch_bounds__(256) void k_gather(const unsigned short* __restrict__ hsb,
                                                const int* __restrict__ offL,
                                                const int* __restrict__ part,
                                                const int2* __restrict__ pairs,
                                                float* __restrict__ h_new) {
    int wid = (blockIdx.x * blockDim.x + threadIdx.x) >> 6;
    int lane = threadIdx.x & 63;
    if (wid >= NDST) return;
    int b = offL[wid] + part[wid >> 8];
    int e2 = (wid + 1 < NDST) ? (offL[wid + 1] + part[(wid + 1) >> 8]) : NEDGE;
    int deg = e2 - b;
    const int half = lane >> 5;
    const int c8 = lane & 31;
    float a0 = 0.f, a1 = 0.f, a2 = 0.f, a3 = 0.f, wsum = 0.f;

    for (int base = 0; base < deg; base += 64) {
        int cnt = min(deg - base, 64);
        int myS = 0;
        float myW = 0.f;
        if (lane < cnt) {
            int2 p = pairs[b + base + lane];
            myS = p.x;
            myW = __int_as_float(p.y);
        }
        wsum += myW;

        int j = 0;
        for (; j + 8 <= cnt; j += 8) {
            #pragma unroll
            for (int q = 0; q < 4; ++q) {
                int jj = j + 2 * q + half;
                int s0 = __shfl(myS, jj);
                float w0 = __shfl(myW, jj);
                uint2 v = *reinterpret_cast<const uint2*>(hsb + (size_t)s0 * DIM + c8 * 4);
                a0 += w0 * bf2f(v.x & 0xFFFFu);
                a1 += w0 * bf2f(v.x >> 16);
                a2 += w0 * bf2f(v.y & 0xFFFFu);
                a3 += w0 * bf2f(v.y >> 16);
            }
        }
        for (; j < cnt; j += 2) {
            int jj = j + half;
            int s0 = __shfl(myS, jj);
            float w0 = __shfl(myW, jj);
            uint2 v = *reinterpret_cast<const uint2*>(hsb + (size_t)s0 * DIM + c8 * 4);
            a0 += w0 * bf2f(v.x & 0xFFFFu);
            a1 += w0 * bf2f(v.x >> 16);
            a2 += w0 * bf2f(v.y & 0xFFFFu);
            a3 += w0 * bf2f(v.y >> 16);
        }
    }

    a0 += __shfl_xor(a0, 32);
    a1 += __shfl_xor(a1, 32);
    a2 += __shfl_xor(a2, 32);
    a3 += __shfl_xor(a3, 32);
    #pragma unroll
    for (int m = 1; m < 64; m <<= 1) wsum += __shfl_xor(wsum, m);

    float inv = (deg > 0) ? 1.f / wsum : 0.f;  // zero-degree dst -> 0 row (matches ref)
    if (half == 0) {
        reinterpret_cast<float4*>(h_new + (size_t)wid * DIM)[c8]
            = make_float4(a0 * inv, a1 * inv, a2 * inv, a3 * inv);
    }
}

// per-column sum / sumsq over h_new
__global__ __launch_bounds__(256) void k_bnstats(const float* __restrict__ h,
                                                 float* __restrict__ colsum,
                                                 float* __restrict__ colsq) {
    int col = threadIdx.x & 127;
    int rp = threadIdx.x >> 7;
    float s = 0.f, q = 0.f;
    for (int r = blockIdx.x * 2 + rp; r < NDST; r += gridDim.x * 2) {
        float x = h[(size_t)r * DIM + col];
        s += x;
        q += x * x;
    }
    __shared__ float ls[2][128], lq[2][128];
    ls[rp][col] = s;
    lq[rp][col] = q;
    __syncthreads();
    if (rp == 0) {
        atomicAdd(&colsum[col], ls[0][col] + ls[1][col]);
        atomicAdd(&colsq[col], lq[0][col] + lq[1][col]);
    }
}

// BN scale/shift computed per-thread in registers (col block fixed under grid-stride)
__global__ __launch_bounds__(256) void k_bnfinal(float* __restrict__ h,
                                                 const float* __restrict__ colsum,
                                                 const float* __restrict__ colsq,
                                                 const float* __restrict__ gamma,
                                                 const float* __restrict__ beta,
                                                 const float* __restrict__ alpha_p) {
    const size_t total4 = (size_t)NDST * DIM / 4;
    const float alpha = alpha_p[0];
    const float invN = 1.f / (float)NDST;
    const int c0 = (threadIdx.x & 31) * 4;
    float sc[4], sh[4];
    #pragma unroll
    for (int k = 0; k < 4; ++k) {
        float mean = colsum[c0 + k] * invN;
        float var = colsq[c0 + k] * invN - mean * mean;
        float s = gamma[c0 + k] * rsqrtf(var + BN_EPS);
        sc[k] = s;
        sh[k] = beta[c0 + k] - mean * s;
    }
    size_t stride = (size_t)gridDim.x * blockDim.x;
    for (size_t i = blockIdx.x * blockDim.x + threadIdx.x; i < total4; i += stride) {
        float4 x = reinterpret_cast<float4*>(h)[i];
        float y0 = x.x * sc[0] + sh[0];
        float y1 = x.y * sc[1] + sh[1];
        float y2 = x.z * sc[2] + sh[2];
        float y3 = x.w * sc[3] + sh[3];
        float4 o;
        o.x = y0 >= 0.f ? y0 : alpha * y0;
        o.y = y1 >= 0.f ? y1 : alpha * y1;
        o.z = y2 >= 0.f ? y2 : alpha * y2;
        o.w = y3 >= 0.f ? y3 : alpha * y3;
        reinterpret_cast<float4*>(h)[i] = o;
    }
}

extern "C" void kernel_launch(void* const* d_in, const int* in_sizes, int n_in,
                              void* d_out, int out_size, void* d_ws, size_t ws_size,
                              hipStream_t stream) {
    const float* src_feat   = (const float*)d_in[0];
    const float* dst_feat   = (const float*)d_in[1];
    const float* edge_feats = (const float*)d_in[2];
    const int*   src_idx    = (const int*)d_in[3];
    const int*   dst_idx    = (const int*)d_in[4];
    const float* W_src      = (const float*)d_in[5];
    const float* b_src      = (const float*)d_in[6];
    const float* W_dst      = (const float*)d_in[7];
    const float* b_dst      = (const float*)d_in[8];
    const float* W_edge     = (const float*)d_in[9];
    const float* b_edge     = (const float*)d_in[10];
    const float* attn_w     = (const float*)d_in[11];
    const float* attn_b     = (const float*)d_in[12];
    const float* gamma      = (const float*)d_in[13];
    const float* beta       = (const float*)d_in[14];
    const float* alpha      = (const float*)d_in[15];

    float* ws      = (float*)d_ws;
    unsigned short* hsb = (unsigned short*)(ws + OFF_HS);
    float* s_score = ws + OFF_SSCORE;
    float* d_score = ws + OFF_DSCORE;
    int*   deg16   = (int*)(ws + OFF_DEG16);
    float* colsum  = ws + OFF_COLSUM;
    float* colsq   = ws + OFF_COLSQ;
    int*   offL    = (int*)(ws + OFF_OFFS);
    int2*  rew     = (int2*)(ws + OFF_REW);
    int2*  pairs   = (int2*)(ws + OFF_PAIRS);
    float* wd_vec  = ws + OFF_WDVEC;
    float* we_vec  = ws + OFF_WEVEC;
    float* scal    = ws + OFF_SCAL;
    float* ws_vec  = ws + OFF_WSVEC;
    int*   part    = (int*)(ws + OFF_PART);
    unsigned short* wt = (unsigned short*)(ws + OFF_WT);

    float* h_new = (float*)d_out;

    // deg16 + colsum + colsq contiguous: one memset (3.2MB)
    hipMemsetAsync(deg16, 0, ((size_t)NDST * 16 + 256) * sizeof(int), stream);

    k_prepwt<<<19, 256, 0, stream>>>(W_dst, b_dst, W_edge, b_edge, W_src, b_src,
                                     attn_w, attn_b, wd_vec, we_vec, ws_vec, scal, wt);
    k_score<<<2 * SCORE_BLK, 256, 0, stream>>>(src_feat, dst_feat, ws_vec, wd_vec,
                                               scal, s_score, d_score);
    k_fused<<<FUSE_GRID, 256, 0, stream>>>(src_feat, wt, b_src, edge_feats,
                                           src_idx, dst_idx, s_score, d_score,
                                           we_vec, scal, hsb, rew, deg16);
    k_scanA<<<SCAN_NBLK, 256, 0, stream>>>(deg16, offL, part);
    k_scanB<<<1, 256, 0, stream>>>(part);
    k_scat<<<SC_BLOCKS, 256, 0, stream>>>(src_idx, dst_idx, rew, offL, part, pairs);
    k_gather<<<(NDST * 64 + 255) / 256, 256, 0, stream>>>(hsb, offL, part, pairs, h_new);
    k_bnstats<<<512, 256, 0, stream>>>(h_new, colsum, colsq);
    k_bnfinal<<<1024, 256, 0, stream>>>(h_new, colsum, colsq, gamma, beta, alpha);
}

// Round 14
// 134.571 us; speedup vs baseline: 1.0667x; 1.0667x over previous
//
#include <hip/hip_runtime.h>
#include <cstddef>

#define NSRC 50000
#define NDST 50000
#define NEDGE 500000
#define DIM 128
#define EDIM 11
#define BN_EPS 1e-5f
#define SCAN_NBLK ((NDST + 255) / 256)   // 196

#define HS_BLOCKS ((NSRC + 63) / 64)      // 782 (GEMM, 64 rows/block)
#define SCB       ((NSRC + 127) / 128)    // 391 (score, 128 rows/block, src or dst)
#define EDB       ((NEDGE + 511) / 512)   // 977 (edge pass, 2 edges/thread)
#define SC_BLOCKS ((NEDGE + 1023) / 1024) // 489 (k_scat, 4 edges/thread)
// groups of 13: 4 GEMM + 4 score + 5 edge; 196 groups covers 784/784/980
#define FUSE_GRID (196 * 13)

typedef short bf16x8 __attribute__((ext_vector_type(8)));
typedef float f32x4 __attribute__((ext_vector_type(4)));

// ---------------- workspace layout (4B elems) ----------------
#define OFF_HS       0                                   // bf16[NSRC][DIM]
#define OFF_SSCORE   (OFF_HS + (size_t)NSRC*DIM/2)
#define OFF_DSCORE   (OFF_SSCORE + NSRC)
#define OFF_DEG16    (OFF_DSCORE + NDST)                 // int[NDST*16] padded counters
#define OFF_COLSUM   (OFF_DEG16 + (size_t)NDST*16)       // deg16..colsq contiguous memset
#define OFF_COLSQ    (OFF_COLSUM + 128)
#define OFF_OFFS     (OFF_COLSQ + 128)                   // offL[NDST] (local prefixes)
#define OFF_EER      (OFF_OFFS + NDST + 2)               // int2[NEDGE]: (rank, ee bits)
#define OFF_PAIRS    (OFF_EER + 2*(size_t)NEDGE)         // int2[NEDGE]
#define OFF_WDVEC    (OFF_PAIRS + 2*(size_t)NEDGE)
#define OFF_WEVEC    (OFF_WDVEC + 128)
#define OFF_SCAL     (OFF_WEVEC + 16)
#define OFF_WSVEC    (OFF_SCAL + 4)
#define OFF_PART     (OFF_WSVEC + 128)
#define OFF_WT       (((OFF_PART + 256 + 3) / 4) * 4)    // 16B-aligned; bf16[128][128]

// fp32 -> bf16 round-to-nearest-even
__device__ __forceinline__ unsigned short f2bf(float x) {
    unsigned int u = __float_as_uint(x);
    u += 0x7FFFu + ((u >> 16) & 1u);
    return (unsigned short)(u >> 16);
}
__device__ __forceinline__ float bf2f(unsigned int u16) {
    return __uint_as_float(u16 << 16);
}

// merged prep + Wt transpose:
// bb=0: wd_vec=W_dst@aw_d, scal[0];  bb=1: we_vec=W_edge@aw_e, scal[1];
// bb=2: ws_vec=W_src@aw_s, scal[2];  bb>=3: Wt[c][k]=bf16(W_src[k][c]) tile bb-3.
__global__ __launch_bounds__(256) void k_prepwt(const float* __restrict__ W_dst,
                                                const float* __restrict__ b_dst,
                                                const float* __restrict__ W_edge,
                                                const float* __restrict__ b_edge,
                                                const float* __restrict__ W_src,
                                                const float* __restrict__ b_src,
                                                const float* __restrict__ attn_w,
                                                const float* __restrict__ attn_b,
                                                float* __restrict__ wd_vec,
                                                float* __restrict__ we_vec,
                                                float* __restrict__ ws_vec,
                                                float* __restrict__ scal,
                                                unsigned short* __restrict__ wt) {
    int bb = blockIdx.x;
    int t = threadIdx.x;
    __shared__ float red[128];
    __shared__ float tile[32][33];
    if (bb == 0) {
        if (t < 128) {
            float acc = 0.f;
            for (int d = 0; d < DIM; ++d) acc += W_dst[t * DIM + d] * attn_w[DIM + d];
            wd_vec[t] = acc;
            red[t] = b_dst[t] * attn_w[DIM + t];
        }
        __syncthreads();
        for (int s = 64; s > 0; s >>= 1) { if (t < s) red[t] += red[t + s]; __syncthreads(); }
        if (t == 0) scal[0] = red[0];
    } else if (bb == 1) {
        if (t < 128) {
            if (t < EDIM) {
                float e = 0.f;
                for (int d = 0; d < DIM; ++d) e += W_edge[t * DIM + d] * attn_w[2 * DIM + d];
                we_vec[t] = e;
            }
            red[t] = b_edge[t] * attn_w[2 * DIM + t];
        }
        __syncthreads();
        for (int s = 64; s > 0; s >>= 1) { if (t < s) red[t] += red[t + s]; __syncthreads(); }
        if (t == 0) scal[1] = red[0] + attn_b[0];
    } else if (bb == 2) {
        if (t < 128) {
            float acc = 0.f;
            for (int d = 0; d < DIM; ++d) acc += W_src[t * DIM + d] * attn_w[d];
            ws_vec[t] = acc;
            red[t] = b_src[t] * attn_w[t];
        }
        __syncthreads();
        for (int s = 64; s > 0; s >>= 1) { if (t < s) red[t] += red[t + s]; __syncthreads(); }
        if (t == 0) scal[2] = red[0];
    } else {
        int idx = bb - 3;
        int bi = idx & 3;   // k-tile
        int bj = idx >> 2;  // c-tile
        int cl = t & 31;
        #pragma unroll
        for (int i = 0; i < 4; ++i) {
            int kl = (t >> 5) * 4 + i;
            tile[kl][cl] = W_src[(size_t)(bi * 32 + kl) * DIM + bj * 32 + cl];
        }
        __syncthreads();
        int ko = t & 31;
        #pragma unroll
        for (int i = 0; i < 4; ++i) {
            int co = (t >> 5) * 4 + i;
            wt[(size_t)(bj * 32 + co) * DIM + bi * 32 + ko] = f2bf(tile[ko][co]);
        }
    }
}

// Fused, 13-block groups (4 GEMM + 4 score + 5 edge). All roles independent:
//   GEMM:  hs = bf16MFMA(src_feat, Wt) + bias -> packed bf16 stores
//   score: s_score/d_score matvec (128 rows/block, 2 lanes/row)
//   edge:  ee = ef.we_vec + scal1; rank via returning atomic; eer[e]=(rank,ee)
__global__ __launch_bounds__(256, 2) void k_fused(const float* __restrict__ A,
                                               const unsigned short* __restrict__ wt,
                                               const float* __restrict__ bias,
                                               const float* __restrict__ ef,
                                               const float* __restrict__ dst_feat,
                                               const int* __restrict__ dst_idx,
                                               const float* __restrict__ ws_vec,
                                               const float* __restrict__ wd_vec,
                                               const float* __restrict__ we_vec,
                                               const float* __restrict__ scal,
                                               unsigned short* __restrict__ hsb,
                                               float* __restrict__ s_score,
                                               float* __restrict__ d_score,
                                               int2* __restrict__ eer,
                                               int* __restrict__ deg16) {
    const int g = blockIdx.x / 13;
    const int sl = blockIdx.x % 13;
    const int t = threadIdx.x;

    if (sl < 4) {
        // ---- GEMM role: 64x128 output tile, 4 waves x (16 rows x 128 cols) ----
        const int hb = g * 4 + sl;
        if (hb >= HS_BLOCKS) return;
        const int wv = t >> 6;
        const int lane = t & 63;
        const int lrow = lane & 15;
        const int kg = lane >> 4;
        const int grow = hb * 64 + wv * 16 + lrow;
        const bool rowok = grow < NSRC;
        const float* arow = A + (size_t)grow * DIM;

        bf16x8 af[4];
        #pragma unroll
        for (int s = 0; s < 4; ++s) {
            float4 p0 = make_float4(0.f, 0.f, 0.f, 0.f), p1 = p0;
            if (rowok) {
                p0 = *reinterpret_cast<const float4*>(arow + 32 * s + kg * 8);
                p1 = *reinterpret_cast<const float4*>(arow + 32 * s + kg * 8 + 4);
            }
            bf16x8 a;
            a[0] = (short)f2bf(p0.x); a[1] = (short)f2bf(p0.y);
            a[2] = (short)f2bf(p0.z); a[3] = (short)f2bf(p0.w);
            a[4] = (short)f2bf(p1.x); a[5] = (short)f2bf(p1.y);
            a[6] = (short)f2bf(p1.z); a[7] = (short)f2bf(p1.w);
            af[s] = a;
        }

        f32x4 acc[8];
        #pragma unroll
        for (int c = 0; c < 8; ++c) acc[c] = (f32x4){0.f, 0.f, 0.f, 0.f};

        #pragma unroll
        for (int c = 0; c < 8; ++c) {
            #pragma unroll
            for (int s = 0; s < 4; ++s) {
                const bf16x8 b = *reinterpret_cast<const bf16x8*>(
                    wt + ((size_t)(16 * c + lrow) * DIM + 32 * s + kg * 8));
                acc[c] = __builtin_amdgcn_mfma_f32_16x16x32_bf16(af[s], b, acc[c], 0, 0, 0);
            }
        }

        const int orow0 = hb * 64 + wv * 16 + kg * 4;
        #pragma unroll
        for (int c = 0; c < 8; ++c) {
            float bb = bias[16 * c + lrow];
            #pragma unroll
            for (int i = 0; i < 4; ++i) {
                unsigned int mybf = f2bf(acc[c][i] + bb);
                unsigned int nb = (unsigned int)__shfl_xor((int)mybf, 1);
                int orow = orow0 + i;
                if ((lrow & 1) == 0 && orow < NSRC) {
                    *reinterpret_cast<unsigned int*>(hsb + (size_t)orow * DIM + 16 * c + lrow)
                        = (mybf & 0xFFFFu) | (nb << 16);
                }
            }
        }
    } else if (sl < 8) {
        // ---- score role: 128 rows/block, 2 lanes/row (64 floats each) ----
        int idx = g * 4 + (sl - 4);
        const float* X;
        const float* V;
        float* out;
        float c;
        if (idx < SCB) {
            X = A; V = ws_vec; out = s_score; c = scal[2];
        } else {
            idx -= SCB;
            if (idx >= SCB) return;
            X = dst_feat; V = wd_vec; out = d_score; c = scal[0];
        }
        int row = idx * 128 + (t >> 1);
        int c0 = (t & 1) * 64;
        if (row >= NDST) return;
        const float4* x = reinterpret_cast<const float4*>(X + (size_t)row * DIM + c0);
        const float4* w = reinterpret_cast<const float4*>(V + c0);
        float p = 0.f;
        #pragma unroll
        for (int i = 0; i < 16; ++i) {
            float4 a = x[i], b = w[i];
            p += a.x * b.x + a.y * b.y + a.z * b.z + a.w * b.w;
        }
        p += __shfl_xor(p, 1);
        if ((t & 1) == 0) out[row] = p + c;
    } else {
        // ---- edge role: ee + returning histogram atomic, packed 8B store ----
        const int eb = g * 5 + (sl - 8);
        if (eb >= EDB) return;
        float wvv[EDIM];
        #pragma unroll
        for (int k = 0; k < EDIM; ++k) wvv[k] = we_vec[k];
        const float s1 = scal[1];
        int ebase = eb * 512 + t;
        #pragma unroll
        for (int i = 0; i < 2; ++i) {
            int e = ebase + i * 256;
            if (e < NEDGE) {
                int d = dst_idx[e];
                const float* er = ef + (size_t)e * EDIM;
                float a = s1;
                #pragma unroll
                for (int k = 0; k < EDIM; ++k) a += er[k] * wvv[k];
                int r = atomicAdd(&deg16[(size_t)d * 16], 1);
                eer[e] = make_int2(r, __float_as_int(a));
            }
        }
    }
}

// ---- scan: A (per-chunk local prefix + block totals), B (scan totals).
// Final off[i] = offL[i] + part[i>>8], computed on the fly by consumers.
__global__ __launch_bounds__(256) void k_scanA(const int* __restrict__ deg16,
                                               int* __restrict__ offL,
                                               int* __restrict__ partials) {
    __shared__ int tmp[256];
    int t = threadIdx.x;
    int i = blockIdx.x * 256 + t;
    int v = (i < NDST) ? deg16[(size_t)i * 16] : 0;
    tmp[t] = v;
    __syncthreads();
    #pragma unroll
    for (int d = 1; d < 256; d <<= 1) {
        int u = (t >= d) ? tmp[t - d] : 0;
        __syncthreads();
        tmp[t] += u;
        __syncthreads();
    }
    if (i < NDST) offL[i] = tmp[t] - v;
    if (t == 255) partials[blockIdx.x] = tmp[255];
}

__global__ __launch_bounds__(256) void k_scanB(int* __restrict__ partials) {
    __shared__ int tmp[256];
    int t = threadIdx.x;
    int v = (t < SCAN_NBLK) ? partials[t] : 0;
    tmp[t] = v;
    __syncthreads();
    #pragma unroll
    for (int d = 1; d < 256; d <<= 1) {
        int u = (t >= d) ? tmp[t - d] : 0;
        __syncthreads();
        tmp[t] += u;
        __syncthreads();
    }
    if (t < SCAN_NBLK) partials[t] = tmp[t] - v;
}

// permutation + exp: pos = offL[d]+part[d>>8]+rank; w = exp(ee + sscore + dscore)
__global__ __launch_bounds__(256) void k_scat(const int* __restrict__ src_idx,
                                              const int* __restrict__ dst_idx,
                                              const int2* __restrict__ eer,
                                              const float* __restrict__ s_score,
                                              const float* __restrict__ d_score,
                                              const int* __restrict__ offL,
                                              const int* __restrict__ part,
                                              int2* __restrict__ pairs) {
    int base = blockIdx.x * 1024 + threadIdx.x;
    #pragma unroll
    for (int i = 0; i < 4; ++i) {
        int e = base + i * 256;
        if (e < NEDGE) {
            int s = src_idx[e], d = dst_idx[e];
            int2 re = eer[e];
            // 0.05-scaled weights => |logit| O(3); exp w/o max-subtraction is
            // exact softmax algebraically and overflow-free here.
            float w = expf(__int_as_float(re.y) + s_score[s] + d_score[d]);
            int pos = offL[d] + part[d >> 8] + re.x;
            pairs[pos] = make_int2(s, __float_as_int(w));
        }
    }
}

// one wave per dst row, 2 edges per instruction (lanes 0-31 / 32-63).
__global__ __launch_bounds__(256) void k_gather(const unsigned short* __restrict__ hsb,
                                                const int* __restrict__ offL,
                                                const int* __restrict__ part,
                                                const int2* __restrict__ pairs,
                                                float* __restrict__ h_new) {
    int wid = (blockIdx.x * blockDim.x + threadIdx.x) >> 6;
    int lane = threadIdx.x & 63;
    if (wid >= NDST) return;
    int b = offL[wid] + part[wid >> 8];
    int e2 = (wid + 1 < NDST) ? (offL[wid + 1] + part[(wid + 1) >> 8]) : NEDGE;
    int deg = e2 - b;
    const int half = lane >> 5;
    const int c8 = lane & 31;
    float a0 = 0.f, a1 = 0.f, a2 = 0.f, a3 = 0.f, wsum = 0.f;

    for (int base = 0; base < deg; base += 64) {
        int cnt = min(deg - base, 64);
        int myS = 0;
        float myW = 0.f;
        if (lane < cnt) {
            int2 p = pairs[b + base + lane];
            myS = p.x;
            myW = __int_as_float(p.y);
        }
        wsum += myW;

        int j = 0;
        for (; j + 8 <= cnt; j += 8) {
            #pragma unroll
            for (int q = 0; q < 4; ++q) {
                int jj = j + 2 * q + half;
                int s0 = __shfl(myS, jj);
                float w0 = __shfl(myW, jj);
                uint2 v = *reinterpret_cast<const uint2*>(hsb + (size_t)s0 * DIM + c8 * 4);
                a0 += w0 * bf2f(v.x & 0xFFFFu);
                a1 += w0 * bf2f(v.x >> 16);
                a2 += w0 * bf2f(v.y & 0xFFFFu);
                a3 += w0 * bf2f(v.y >> 16);
            }
        }
        for (; j < cnt; j += 2) {
            int jj = j + half;
            int s0 = __shfl(myS, jj);
            float w0 = __shfl(myW, jj);
            uint2 v = *reinterpret_cast<const uint2*>(hsb + (size_t)s0 * DIM + c8 * 4);
            a0 += w0 * bf2f(v.x & 0xFFFFu);
            a1 += w0 * bf2f(v.x >> 16);
            a2 += w0 * bf2f(v.y & 0xFFFFu);
            a3 += w0 * bf2f(v.y >> 16);
        }
    }

    a0 += __shfl_xor(a0, 32);
    a1 += __shfl_xor(a1, 32);
    a2 += __shfl_xor(a2, 32);
    a3 += __shfl_xor(a3, 32);
    #pragma unroll
    for (int m = 1; m < 64; m <<= 1) wsum += __shfl_xor(wsum, m);

    float inv = (deg > 0) ? 1.f / wsum : 0.f;  // zero-degree dst -> 0 row (matches ref)
    if (half == 0) {
        reinterpret_cast<float4*>(h_new + (size_t)wid * DIM)[c8]
            = make_float4(a0 * inv, a1 * inv, a2 * inv, a3 * inv);
    }
}

// per-column sum / sumsq over h_new
__global__ __launch_bounds__(256) void k_bnstats(const float* __restrict__ h,
                                                 float* __restrict__ colsum,
                                                 float* __restrict__ colsq) {
    int col = threadIdx.x & 127;
    int rp = threadIdx.x >> 7;
    float s = 0.f, q = 0.f;
    for (int r = blockIdx.x * 2 + rp; r < NDST; r += gridDim.x * 2) {
        float x = h[(size_t)r * DIM + col];
        s += x;
        q += x * x;
    }
    __shared__ float ls[2][128], lq[2][128];
    ls[rp][col] = s;
    lq[rp][col] = q;
    __syncthreads();
    if (rp == 0) {
        atomicAdd(&colsum[col], ls[0][col] + ls[1][col]);
        atomicAdd(&colsq[col], lq[0][col] + lq[1][col]);
    }
}

// BN scale/shift computed per-thread in registers (col block fixed under grid-stride)
__global__ __launch_bounds__(256) void k_bnfinal(float* __restrict__ h,
                                                 const float* __restrict__ colsum,
                                                 const float* __restrict__ colsq,
                                                 const float* __restrict__ gamma,
                                                 const float* __restrict__ beta,
                                                 const float* __restrict__ alpha_p) {
    const size_t total4 = (size_t)NDST * DIM / 4;
    const float alpha = alpha_p[0];
    const float invN = 1.f / (float)NDST;
    const int c0 = (threadIdx.x & 31) * 4;
    float sc[4], sh[4];
    #pragma unroll
    for (int k = 0; k < 4; ++k) {
        float mean = colsum[c0 + k] * invN;
        float var = colsq[c0 + k] * invN - mean * mean;
        float s = gamma[c0 + k] * rsqrtf(var + BN_EPS);
        sc[k] = s;
        sh[k] = beta[c0 + k] - mean * s;
    }
    size_t stride = (size_t)gridDim.x * blockDim.x;
    for (size_t i = blockIdx.x * blockDim.x + threadIdx.x; i < total4; i += stride) {
        float4 x = reinterpret_cast<float4*>(h)[i];
        float y0 = x.x * sc[0] + sh[0];
        float y1 = x.y * sc[1] + sh[1];
        float y2 = x.z * sc[2] + sh[2];
        float y3 = x.w * sc[3] + sh[3];
        float4 o;
        o.x = y0 >= 0.f ? y0 : alpha * y0;
        o.y = y1 >= 0.f ? y1 : alpha * y1;
        o.z = y2 >= 0.f ? y2 : alpha * y2;
        o.w = y3 >= 0.f ? y3 : alpha * y3;
        reinterpret_cast<float4*>(h)[i] = o;
    }
}

extern "C" void kernel_launch(void* const* d_in, const int* in_sizes, int n_in,
                              void* d_out, int out_size, void* d_ws, size_t ws_size,
                              hipStream_t stream) {
    const float* src_feat   = (const float*)d_in[0];
    const float* dst_feat   = (const float*)d_in[1];
    const float* edge_feats = (const float*)d_in[2];
    const int*   src_idx    = (const int*)d_in[3];
    const int*   dst_idx    = (const int*)d_in[4];
    const float* W_src      = (const float*)d_in[5];
    const float* b_src      = (const float*)d_in[6];
    const float* W_dst      = (const float*)d_in[7];
    const float* b_dst      = (const float*)d_in[8];
    const float* W_edge     = (const float*)d_in[9];
    const float* b_edge     = (const float*)d_in[10];
    const float* attn_w     = (const float*)d_in[11];
    const float* attn_b     = (const float*)d_in[12];
    const float* gamma      = (const float*)d_in[13];
    const float* beta       = (const float*)d_in[14];
    const float* alpha      = (const float*)d_in[15];

    float* ws      = (float*)d_ws;
    unsigned short* hsb = (unsigned short*)(ws + OFF_HS);
    float* s_score = ws + OFF_SSCORE;
    float* d_score = ws + OFF_DSCORE;
    int*   deg16   = (int*)(ws + OFF_DEG16);
    float* colsum  = ws + OFF_COLSUM;
    float* colsq   = ws + OFF_COLSQ;
    int*   offL    = (int*)(ws + OFF_OFFS);
    int2*  eer     = (int2*)(ws + OFF_EER);
    int2*  pairs   = (int2*)(ws + OFF_PAIRS);
    float* wd_vec  = ws + OFF_WDVEC;
    float* we_vec  = ws + OFF_WEVEC;
    float* scal    = ws + OFF_SCAL;
    float* ws_vec  = ws + OFF_WSVEC;
    int*   part    = (int*)(ws + OFF_PART);
    unsigned short* wt = (unsigned short*)(ws + OFF_WT);

    float* h_new = (float*)d_out;

    // deg16 + colsum + colsq contiguous: one memset (3.2MB)
    hipMemsetAsync(deg16, 0, ((size_t)NDST * 16 + 256) * sizeof(int), stream);

    k_prepwt<<<19, 256, 0, stream>>>(W_dst, b_dst, W_edge, b_edge, W_src, b_src,
                                     attn_w, attn_b, wd_vec, we_vec, ws_vec, scal, wt);
    k_fused<<<FUSE_GRID, 256, 0, stream>>>(src_feat, wt, b_src, edge_feats,
                                           dst_feat, dst_idx, ws_vec, wd_vec,
                                           we_vec, scal, hsb, s_score, d_score,
                                           eer, deg16);
    k_scanA<<<SCAN_NBLK, 256, 0, stream>>>(deg16, offL, part);
    k_scanB<<<1, 256, 0, stream>>>(part);
    k_scat<<<SC_BLOCKS, 256, 0, stream>>>(src_idx, dst_idx, eer, s_score, d_score,
                                          offL, part, pairs);
    k_gather<<<(NDST * 64 + 255) / 256, 256, 0, stream>>>(hsb, offL, part, pairs, h_new);
    k_bnstats<<<512, 256, 0, stream>>>(h_new, colsum, colsq);
    k_bnfinal<<<1024, 256, 0, stream>>>(h_new, colsum, colsq, gamma, beta, alpha);
}